// Round 10
// baseline (42.504 us; speedup 1.0000x reference)
//
#include <hip/hip_runtime.h>
#include <hip/hip_bf16.h>

#define M 256
#define NOUT 1024
#define KTOT 16384
#define RANK 16
#define NKC 16          // split-K factor
#define KCHUNK 1024     // K per block
#define BK 32           // K per phase
#define NPH 32          // phases per block
#define BO 64           // o-rows per block

typedef __attribute__((ext_vector_type(8)))  short bf16x8_t;
typedef __attribute__((ext_vector_type(4)))  float f32x4_t;
typedef __attribute__((ext_vector_type(16))) float f32x16_t;
typedef __attribute__((ext_vector_type(8)))  unsigned short u16x8_t;

static __device__ __forceinline__ unsigned short f2bf(float f) {
  unsigned u = __builtin_bit_cast(unsigned, f);
  u += 0x7FFFu + ((u >> 16) & 1u);   // round-to-nearest-even
  return (unsigned short)(u >> 16);
}
static __device__ __forceinline__ float bf2f(unsigned short h) {
  unsigned u = ((unsigned)h) << 16;
  return __builtin_bit_cast(float, u);
}
static __device__ __forceinline__ bf16x8_t cvt8(f32x4_t a, f32x4_t b) {
  bf16x8_t r;
  r[0] = (short)f2bf(a[0]); r[1] = (short)f2bf(a[1]);
  r[2] = (short)f2bf(a[2]); r[3] = (short)f2bf(a[3]);
  r[4] = (short)f2bf(b[0]); r[5] = (short)f2bf(b[1]);
  r[6] = (short)f2bf(b[2]); r[7] = (short)f2bf(b[3]);
  return r;
}

// X stored in 32-k chunks, slot-swizzled at build time (rule #21):
//   element (b,k): chunk = k>>5, slot = (k&31)>>3 (0..3), el = k&7
//   pos = ((chunk*256 + b)*4 + (slot ^ (b&3)))*8 + el            (bf16)
// GEMM stages a chunk with a PURE LINEAR copy (1 KB contiguous per wave
// instr); fragment ds_read_b128 at slot (ks*2+l5)^(l31&3) is ~4-way max.
__global__ __launch_bounds__(256) void build_x_kernel(
    const float* __restrict__ input, const float* __restrict__ coef,
    unsigned short* __restrict__ X)
{
  int idx = blockIdx.x * 256 + threadIdx.x;   // idx = b*1024 + i
  int b = idx >> 10, i = idx & 1023;
  float in = input[idx];
  const float* c = coef + b * RANK;
  u16x8_t lo, hi;                              // k = i*16 + r
  #pragma unroll
  for (int r = 0; r < 8; ++r) lo[r] = f2bf(in * c[r]);
  #pragma unroll
  for (int r = 0; r < 8; ++r) hi[r] = f2bf(in * c[8 + r]);
  int chunk = i >> 1;            // (i*16) >> 5
  int s0 = (i & 1) * 2;          // slots s0 (r<8), s0+1 (r>=8)
  int sw = b & 3;
  size_t base = ((size_t)chunk * 256 + b) * 32;    // shorts
  *(u16x8_t*)(X + base + (size_t)((s0    ) ^ sw) * 8) = lo;
  *(u16x8_t*)(X + base + (size_t)((s0 | 1) ^ sw) * 8) = hi;
}

// out^T GEMM: part[kc][o][b] (bf16) = sum_{k in chunk kc} W[o,k] * X[b,k]
// via mfma_f32_32x32x16_bf16 (A = W-frag row->o, B = X-frag col->b).
// Block: 64 o x 256 b x K=1024; 512 threads (8 waves); 96 KB LDS (4 slots
// x (16 KB X + 8 KB W)) -> 1 block/CU. Grid 256 = 16 ot x 16 kc, 1/CU.
//
// DEEP PIPELINE (the point of this round): stage distance 3, counted
// vmcnt(6) + raw s_barrier each phase -- every wave keeps 6-9 staging
// loads (6-9 KB; 48-72 KB/CU) in flight AT ALL TIMES, never draining to
// zero until the epilogue (AITER pattern). Phase p: wait vmcnt(6) [phase
// p landed, p+1/p+2 still in flight], barrier, stage p+3, compute p.
__global__ __launch_bounds__(512, 2) void gemm_kernel(
    const unsigned short* __restrict__ X, const float* __restrict__ W,
    unsigned short* __restrict__ part)
{
  __shared__ unsigned short Xs[4][256 * 4 * 8];   // 4 x 16 KB [b][slot'][8]
  __shared__ float          Wf[4][64 * 8 * 4];    // 4 x  8 KB [o'][slot'][4]

  const int tid = threadIdx.x;                  // 0..511
  const int w = tid >> 6, lane = tid & 63;
  const int l31 = lane & 31, l5 = lane >> 5;
  const int ow = w & 1, btp = w >> 1;           // wave: o-half ow, b-tiles {2btp,2btp+1}

  // XCD pinning: per XCD 2 kc x 16 ot -> X slices (2 x 512 KB) L2-resident.
  const int lin = blockIdx.x;                   // 0..255
  const int idx = lin >> 3;
  const int kc = (lin & 7) * 2 + (idx & 1);
  const int ot = idx >> 1;                      // 0..15

  const int o0 = ot * BO;
  const int kb0 = kc * KCHUNK;

  f32x16_t acc0 = (f32x16_t)(0.0f), acc1 = (f32x16_t)(0.0f);

  // W stage coords: thread t covers 16 B piece (o' = t>>3, slot s = t&7) of
  // the 128 B phase row-chunk; SOURCE slot is s ^ (o'&7) (inverse swizzle),
  // LDS dest linear -> LDS slot s holds source slot s^(o'&7).
  const int wo_ = tid >> 3, ws_ = tid & 7;
  const float* wsrc = W + (size_t)(o0 + wo_) * KTOT + kb0 + ((ws_ ^ (wo_ & 7)) * 4);
  const unsigned short* xbase = X + (size_t)(kc * NPH) * (256 * 32);

  #define SB __builtin_amdgcn_sched_barrier(0);
  #define VM(N) asm volatile("s_waitcnt vmcnt(" #N ")" ::: "memory");

  #define STAGE(P, S)                                                        \
    {                                                                        \
      __builtin_amdgcn_global_load_lds(                                      \
          (const __attribute__((address_space(1))) unsigned int*)            \
              (wsrc + (size_t)(P) * 32),                                     \
          (__attribute__((address_space(3))) unsigned int*)                  \
              (&Wf[S][tid * 4]),                                             \
          16, 0, 0);                                                         \
      _Pragma("unroll")                                                      \
      for (int j = 0; j < 2; ++j) {                                          \
        int q = j * 512 + tid;                                               \
        __builtin_amdgcn_global_load_lds(                                    \
            (const __attribute__((address_space(1))) unsigned int*)          \
                (xbase + (size_t)(P) * 8192 + q * 8),                        \
            (__attribute__((address_space(3))) unsigned int*)                \
                (&Xs[S][q * 8]),                                             \
            16, 0, 0);                                                       \
      }                                                                      \
    }

  #define COMPUTE(S)                                                         \
    {                                                                        \
      _Pragma("unroll")                                                      \
      for (int ks = 0; ks < 2; ++ks) {                                       \
        int o = ow * 32 + l31;                                               \
        f32x4_t a0 = *(const f32x4_t*)                                       \
            &Wf[S][(o * 8 + ((ks * 4 + l5 * 2)     ^ (l31 & 7))) * 4];       \
        f32x4_t a1 = *(const f32x4_t*)                                       \
            &Wf[S][(o * 8 + ((ks * 4 + l5 * 2 + 1) ^ (l31 & 7))) * 4];       \
        bf16x8_t af = cvt8(a0, a1);                                          \
        int b0r = (btp * 2) * 32 + l31;                                      \
        int b1r = (btp * 2 + 1) * 32 + l31;                                  \
        bf16x8_t xf0 = *(const bf16x8_t*)                                    \
            &Xs[S][(b0r * 4 + ((ks * 2 + l5) ^ (l31 & 3))) * 8];             \
        bf16x8_t xf1 = *(const bf16x8_t*)                                    \
            &Xs[S][(b1r * 4 + ((ks * 2 + l5) ^ (l31 & 3))) * 8];             \
        acc0 = __builtin_amdgcn_mfma_f32_32x32x16_bf16(af, xf0, acc0, 0, 0, 0); \
        acc1 = __builtin_amdgcn_mfma_f32_32x32x16_bf16(af, xf1, acc1, 0, 0, 0); \
      }                                                                      \
    }

  // one pipeline step: wait phase p (leave p+1,p+2 in flight), barrier,
  // stage p+3 (back to 9 outstanding), compute p.
  #define ITER(PB, I)                                                        \
    VM(6) SB                                                                 \
    __builtin_amdgcn_s_barrier(); SB                                         \
    STAGE((PB) + (I) + 3, (((I) + 3) & 3)) SB                                \
    __builtin_amdgcn_s_setprio(1);                                           \
    COMPUTE(I)                                                               \
    __builtin_amdgcn_s_setprio(0);

  // ---- prologue: 3 phases in flight (9 instrs/wave) ----
  STAGE(0, 0) STAGE(1, 1) STAGE(2, 2)

  // ---- main: phases 0..27, slots compile-time via x4 unroll ----
  for (int pb = 0; pb < 28; pb += 4) {
    ITER(pb, 0) ITER(pb, 1) ITER(pb, 2) ITER(pb, 3)
  }

  // ---- tail: phases 28..31, counted drain 6 -> 3 -> 0 ----
  VM(6) SB __builtin_amdgcn_s_barrier(); SB STAGE(31, 3) SB
  __builtin_amdgcn_s_setprio(1); COMPUTE(0) __builtin_amdgcn_s_setprio(0);
  VM(6) SB __builtin_amdgcn_s_barrier(); SB
  __builtin_amdgcn_s_setprio(1); COMPUTE(1) __builtin_amdgcn_s_setprio(0);
  VM(3) SB __builtin_amdgcn_s_barrier(); SB
  __builtin_amdgcn_s_setprio(1); COMPUTE(2) __builtin_amdgcn_s_setprio(0);
  VM(0) SB __builtin_amdgcn_s_barrier(); SB
  COMPUTE(3)

  // ---- epilogue: D layout col(b)=l&31, row(o)=(q&3)+8*(q>>2)+4*l5 ----
  unsigned short* p = part + (size_t)kc * (NOUT * 256);
  #pragma unroll
  for (int q = 0; q < 16; ++q) {
    int o = o0 + ow * 32 + (q & 3) + 8 * (q >> 2) + 4 * l5;
    p[(size_t)o * 256 + (btp * 2) * 32 + l31]     = f2bf(acc0[q]);
    p[(size_t)o * 256 + (btp * 2 + 1) * 32 + l31] = f2bf(acc1[q]);
  }
  #undef STAGE
  #undef COMPUTE
  #undef ITER
  #undef VM
  #undef SB
}

// out[b][o] = sum_kc bf2f(part[kc][o][b]) + sum_r bias[o][r]*coef[b][r]
// Block: 8 o-rows x 256 b; coalesced part reads; LDS transpose; coalesced
// out writes.
__global__ __launch_bounds__(256) void reduce_bias_kernel(
    const unsigned short* __restrict__ part, const float* __restrict__ bias,
    const float* __restrict__ coef, float* __restrict__ out)
{
  __shared__ float lds[8 * 256];
  const int t = threadIdx.x;
  const int o = blockIdx.x * 8 + (t >> 5);
  const int b8 = (t & 31) * 8;

  float s[8];
  #pragma unroll
  for (int j = 0; j < 8; ++j) s[j] = 0.f;

  #pragma unroll 8
  for (int kc = 0; kc < NKC; ++kc) {
    u16x8_t v = *(const u16x8_t*)(part + ((size_t)kc * NOUT + o) * 256 + b8);
    #pragma unroll
    for (int j = 0; j < 8; ++j) s[j] += bf2f(v[j]);
  }

  const f32x4_t* br = (const f32x4_t*)(bias + (size_t)o * RANK);
  f32x4_t b0 = br[0], b1 = br[1], b2 = br[2], b3 = br[3];
  #pragma unroll
  for (int j = 0; j < 8; ++j) {
    const f32x4_t* cr = (const f32x4_t*)(coef + (size_t)(b8 + j) * RANK);
    f32x4_t c0 = cr[0], c1 = cr[1], c2 = cr[2], c3 = cr[3];
    float bb = 0.f;
    #pragma unroll
    for (int e = 0; e < 4; ++e)
      bb += b0[e] * c0[e] + b1[e] * c1[e] + b2[e] * c2[e] + b3[e] * c3[e];
    s[j] += bb;
  }

  f32x4_t v0, v1;
  v0[0] = s[0]; v0[1] = s[1]; v0[2] = s[2]; v0[3] = s[3];
  v1[0] = s[4]; v1[1] = s[5]; v1[2] = s[6]; v1[3] = s[7];
  *(f32x4_t*)&lds[(t >> 5) * 256 + b8]     = v0;
  *(f32x4_t*)&lds[(t >> 5) * 256 + b8 + 4] = v1;
  __syncthreads();

  const int b = t;
  float g[8];
  #pragma unroll
  for (int j = 0; j < 8; ++j) g[j] = lds[j * 256 + b];
  float4* dst = (float4*)(out + (size_t)b * NOUT + blockIdx.x * 8);
  dst[0] = make_float4(g[0], g[1], g[2], g[3]);
  dst[1] = make_float4(g[4], g[5], g[6], g[7]);
}

extern "C" void kernel_launch(void* const* d_in, const int* in_sizes, int n_in,
                              void* d_out, int out_size, void* d_ws, size_t ws_size,
                              hipStream_t stream) {
  const float* input = (const float*)d_in[0];   // (256, 1024)
  const float* coef  = (const float*)d_in[1];   // (256, 16)
  const float* W     = (const float*)d_in[2];   // (1024, 1024, 16) -> (1024, 16384)
  const float* bias  = (const float*)d_in[3];   // (1024, 16)
  float* out = (float*)d_out;                   // (256, 1024)

  unsigned short* X    = (unsigned short*)d_ws;                               // 8 MiB bf16
  unsigned short* part = (unsigned short*)((char*)d_ws + (size_t)M * KTOT * 2); // 8 MiB bf16

  build_x_kernel<<<(M * 1024) / 256, 256, 0, stream>>>(input, coef, X);
  gemm_kernel<<<256, 512, 0, stream>>>(X, W, part);
  reduce_bias_kernel<<<NOUT / 8, 256, 0, stream>>>(part, bias, coef, out);
}

// Round 12
// 39.571 us; speedup vs baseline: 1.0741x; 1.0741x over previous
//
#include <hip/hip_runtime.h>
#include <hip/hip_bf16.h>

#define M 256
#define NOUT 1024
#define KTOT 16384
#define RANK 16
#define NKC 32          // split-K factor
#define KCHUNK 512      // K per block
#define BK 32           // K per phase
#define NPH 16          // phases per block
#define BO 128          // o-rows per block

typedef __attribute__((ext_vector_type(8)))  short bf16x8_t;
typedef __attribute__((ext_vector_type(4)))  float f32x4_t;
typedef __attribute__((ext_vector_type(16))) float f32x16_t;
typedef __attribute__((ext_vector_type(8)))  unsigned short u16x8_t;

static __device__ __forceinline__ unsigned short f2bf(float f) {
  unsigned u = __builtin_bit_cast(unsigned, f);
  u += 0x7FFFu + ((u >> 16) & 1u);   // round-to-nearest-even
  return (unsigned short)(u >> 16);
}
static __device__ __forceinline__ float bf2f(unsigned short h) {
  unsigned u = ((unsigned)h) << 16;
  return __builtin_bit_cast(float, u);
}
// convert two float4 (8 contiguous fp32 of one W row) to bf16 and ds_write
// as one 16 B fragment piece. Function args avoid the `w##S##0.x` pp-token
// paste bug that killed R11's compile.
static __device__ __forceinline__ void dsw_fn(unsigned short* dst,
                                              float4 a, float4 b) {
  u16x8_t hv;
  hv[0] = f2bf(a.x); hv[1] = f2bf(a.y); hv[2] = f2bf(a.z); hv[3] = f2bf(a.w);
  hv[4] = f2bf(b.x); hv[5] = f2bf(b.y); hv[6] = f2bf(b.z); hv[7] = f2bf(b.w);
  *(u16x8_t*)dst = hv;
}

// X stored FRAGMENT-MAJOR in 32-k chunks:
//   element (b,k): chunk = k>>5, region = (k&31)>>3 (0..3 = ks*2+l5), e = k&7
//   short-index = chunk*8192 + region*2048 + b*8 + e
// GEMM stages a chunk with a pure LINEAR global_load_lds (16 KB); the
// B-fragment ds_read_b128 (region*4KB + b*16B) is then 32 lanes x 16 B
// CONTIGUOUS per half-wave -> structurally conflict-free.
__global__ __launch_bounds__(256) void build_x_kernel(
    const float* __restrict__ input, const float* __restrict__ coef,
    unsigned short* __restrict__ X)
{
  int idx = blockIdx.x * 256 + threadIdx.x;   // idx = b*1024 + i
  int b = idx >> 10, i = idx & 1023;
  float in = input[idx];
  const float* c = coef + b * RANK;
  u16x8_t lo, hi;                              // k = i*16 + r
  #pragma unroll
  for (int r = 0; r < 8; ++r) lo[r] = f2bf(in * c[r]);
  #pragma unroll
  for (int r = 0; r < 8; ++r) hi[r] = f2bf(in * c[8 + r]);
  // chunk = i>>1; lo -> region (i&1)*2+0, hi -> region (i&1)*2+1
  size_t base = (size_t)(i >> 1) * 8192 + (size_t)((i & 1) * 2) * 2048 + b * 8;
  *(u16x8_t*)(X + base)        = lo;
  *(u16x8_t*)(X + base + 2048) = hi;
}

// out^T GEMM: part[kc][o][b] (bf16) = sum_{k in chunk kc} W[o,k] * X[b,k]
// via mfma_f32_32x32x16_bf16 (A = W-frag row->o, B = X-frag col->b).
// Block: 128 o x 256 b x K=512; 512 threads (8 waves = 2 wr x 4 wc, wave
// tile 64o x 64b: 2 o-frags x 2 b-frags -> 8 MFMAs from 8 reads/k-step).
// Grid 256 = 8 ot x 32 kc -> 1 block/CU; LDS 80 KB.
//
// CONFLICT-FREE LDS (the hypothesis under test): both operands are read as
// contiguous fragment-major ds_read_b128 groups (zero structural conflicts).
// W path: global->reg (contiguous 128 B/row pieces), cvt fp32->bf16 once,
// ds_write_b128 into fragment-major Wl (bf16: half the LDS bytes of R10).
// X path: linear global_load_lds of pre-swizzled fragment-major chunks.
// Pipeline: X 4 slots (stage distance 3), W 3 reg-sets (distance 2),
// Wl double-buffered; ONE raw s_barrier per phase; vmcnt(6) floor keeps
// >=6 loads in flight through the whole main loop (X(p),W(p) are the 4
// oldest of 10 -> retire exactly to 6); tail phases rely on the compiler's
// register-dependency waits, which retire the older X entries too.
__global__ __launch_bounds__(512, 2) void gemm_kernel(
    const unsigned short* __restrict__ X, const float* __restrict__ W,
    unsigned short* __restrict__ part)
{
  __shared__ __align__(16) unsigned short Xs[4][8192];   // 4 x 16 KB
  __shared__ __align__(16) unsigned short Wl[2][4096];   // 2 x  8 KB

  const int tid = threadIdx.x;                  // 0..511
  const int wid = tid >> 6, lane = tid & 63;
  const int l31 = lane & 31, l5 = lane >> 5;
  const int wr = wid >> 2, wc = wid & 3;        // 2 x 4 wave grid

  // XCD pinning: kc group fixed by lin&7 -> the 8 ot-blocks sharing a kc
  // X-slice (256 KB) land on one XCD's L2 (4 slices/XCD = 1 MB).
  const int lin = blockIdx.x;                   // 0..255
  const int kc = (lin & 7) * 4 + ((lin >> 3) & 3);
  const int ot = lin >> 5;                      // 0..7

  const int o0 = ot * BO;
  const int kb0 = kc * KCHUNK;

  f32x16_t a00 = (f32x16_t)(0.0f), a01 = (f32x16_t)(0.0f);
  f32x16_t a10 = (f32x16_t)(0.0f), a11 = (f32x16_t)(0.0f);

  // W stage coords: thread t covers row = t>>2 (0..127), q = t&3 ->
  // 8 contiguous fp32 at k = phase*32 + q*8 (two float4 loads; 4 threads
  // cover a full 128 B row-line). LDS dest: [ofrag(4)][region=q][row&31][8].
  const int wrow = tid >> 2, wq = tid & 3;
  const float* wgp = W + (size_t)(o0 + wrow) * KTOT + kb0 + wq * 8;
  const int widx = (((tid >> 7) * 4 + wq) * 32 + (wrow & 31)) * 8;
  const unsigned short* xbase = X + (size_t)kc * NPH * 8192;

  float4 wA0, wA1, wB0, wB1, wC0, wC1;

  #define SB __builtin_amdgcn_sched_barrier(0);

  #define LOADW(S, P)                                                        \
    { w##S##0 = *(const float4*)(wgp + (P) * 32);                            \
      w##S##1 = *(const float4*)(wgp + (P) * 32 + 4); }

  #define DSW(S, PB) dsw_fn(&Wl[PB][widx], w##S##0, w##S##1);

  #define STX(P, SL)                                                         \
    { _Pragma("unroll")                                                      \
      for (int j = 0; j < 2; ++j) {                                          \
        int q = j * 512 + tid;                                               \
        __builtin_amdgcn_global_load_lds(                                    \
            (const __attribute__((address_space(1))) unsigned int*)          \
                (xbase + (size_t)(P) * 8192 + q * 8),                        \
            (__attribute__((address_space(3))) unsigned int*)                \
                (&Xs[SL][q * 8]),                                            \
            16, 0, 0);                                                       \
      } }

  #define COMP(XS, PB)                                                      \
    { _Pragma("unroll")                                                     \
      for (int ks = 0; ks < 2; ++ks) {                                      \
        bf16x8_t af0 = *(const bf16x8_t*)                                   \
            &Wl[PB][(((wr * 2 + 0) * 4 + ks * 2 + l5) * 32 + l31) * 8];     \
        bf16x8_t af1 = *(const bf16x8_t*)                                   \
            &Wl[PB][(((wr * 2 + 1) * 4 + ks * 2 + l5) * 32 + l31) * 8];     \
        bf16x8_t xf0 = *(const bf16x8_t*)                                   \
            &Xs[XS][((ks * 2 + l5) * 256 + wc * 64 + l31) * 8];             \
        bf16x8_t xf1 = *(const bf16x8_t*)                                   \
            &Xs[XS][((ks * 2 + l5) * 256 + wc * 64 + 32 + l31) * 8];        \
        a00 = __builtin_amdgcn_mfma_f32_32x32x16_bf16(af0, xf0, a00, 0, 0, 0); \
        a01 = __builtin_amdgcn_mfma_f32_32x32x16_bf16(af0, xf1, a01, 0, 0, 0); \
        a10 = __builtin_amdgcn_mfma_f32_32x32x16_bf16(af1, xf0, a10, 0, 0, 0); \
        a11 = __builtin_amdgcn_mfma_f32_32x32x16_bf16(af1, xf1, a11, 0, 0, 0); \
      } }

  // One phase: retire (X(p), W(p)) via vmcnt(6) [the 4 oldest of the 10 in
  // flight], write W(p) to Wl[p&1], barrier, issue W(p+2)+X(p+3), compute(p).
  #define PHASE(P, CS, NS, XC, XI, DOW, DOX)                                 \
    asm volatile("s_waitcnt vmcnt(6)" ::: "memory"); SB                      \
    DSW(CS, (P) & 1)                                                         \
    asm volatile("s_waitcnt lgkmcnt(0)" ::: "memory"); SB                    \
    __builtin_amdgcn_s_barrier(); SB                                         \
    if (DOW) { LOADW(NS, (P) + 2) }                                          \
    if (DOX) { STX((P) + 3, XI) }                                            \
    SB                                                                       \
    __builtin_amdgcn_s_setprio(1);                                           \
    COMP(XC, (P) & 1)                                                        \
    __builtin_amdgcn_s_setprio(0);

  // ---- prologue: queue = [X0, W0, X1, W1, X2] (10 instrs) ----
  STX(0, 0) SB
  LOADW(A, 0) SB
  STX(1, 1) SB
  LOADW(B, 1) SB
  STX(2, 2) SB

  // ---- 16 straight-line phases ----
  PHASE(0,  A, C, 0, 3, 1, 1)
  PHASE(1,  B, A, 1, 0, 1, 1)
  PHASE(2,  C, B, 2, 1, 1, 1)
  PHASE(3,  A, C, 3, 2, 1, 1)
  PHASE(4,  B, A, 0, 3, 1, 1)
  PHASE(5,  C, B, 1, 0, 1, 1)
  PHASE(6,  A, C, 2, 1, 1, 1)
  PHASE(7,  B, A, 3, 2, 1, 1)
  PHASE(8,  C, B, 0, 3, 1, 1)
  PHASE(9,  A, C, 1, 0, 1, 1)
  PHASE(10, B, A, 2, 1, 1, 1)
  PHASE(11, C, B, 3, 2, 1, 1)
  PHASE(12, A, C, 0, 3, 1, 1)
  PHASE(13, B, A, 1, 0, 1, 0)
  PHASE(14, C, B, 2, 1, 0, 0)
  PHASE(15, A, C, 3, 2, 0, 0)

  // ---- epilogue: D layout col(b)=l&31, row(o)=(q&3)+8*(q>>2)+4*l5 ----
  unsigned short* pp = part + (size_t)kc * (NOUT * 256);
  #pragma unroll
  for (int q = 0; q < 16; ++q) {
    int oo = o0 + wr * 64 + (q & 3) + 8 * (q >> 2) + 4 * l5;
    int cb = wc * 64 + l31;
    pp[(size_t)oo * 256 + cb]             = f2bf(a00[q]);
    pp[(size_t)oo * 256 + cb + 32]        = f2bf(a01[q]);
    pp[(size_t)(oo + 32) * 256 + cb]      = f2bf(a10[q]);
    pp[(size_t)(oo + 32) * 256 + cb + 32] = f2bf(a11[q]);
  }
  #undef LOADW
  #undef DSW
  #undef STX
  #undef COMP
  #undef PHASE
  #undef SB
}

// out[b][o] = sum_kc bf2f(part[kc][o][b]) + sum_r bias[o][r]*coef[b][r]
// Block: 8 o-rows x 256 b; coalesced part reads; LDS transpose; coalesced
// out writes.
__global__ __launch_bounds__(256) void reduce_bias_kernel(
    const unsigned short* __restrict__ part, const float* __restrict__ bias,
    const float* __restrict__ coef, float* __restrict__ out)
{
  __shared__ float lds[8 * 256];
  const int t = threadIdx.x;
  const int o = blockIdx.x * 8 + (t >> 5);
  const int b8 = (t & 31) * 8;

  float s[8];
  #pragma unroll
  for (int j = 0; j < 8; ++j) s[j] = 0.f;

  #pragma unroll 8
  for (int kc = 0; kc < NKC; ++kc) {
    u16x8_t v = *(const u16x8_t*)(part + ((size_t)kc * NOUT + o) * 256 + b8);
    #pragma unroll
    for (int j = 0; j < 8; ++j) s[j] += bf2f(v[j]);
  }

  const f32x4_t* br = (const f32x4_t*)(bias + (size_t)o * RANK);
  f32x4_t b0 = br[0], b1 = br[1], b2 = br[2], b3 = br[3];
  #pragma unroll
  for (int j = 0; j < 8; ++j) {
    const f32x4_t* cr = (const f32x4_t*)(coef + (size_t)(b8 + j) * RANK);
    f32x4_t c0 = cr[0], c1 = cr[1], c2 = cr[2], c3 = cr[3];
    float bb = 0.f;
    #pragma unroll
    for (int e = 0; e < 4; ++e)
      bb += b0[e] * c0[e] + b1[e] * c1[e] + b2[e] * c2[e] + b3[e] * c3[e];
    s[j] += bb;
  }

  f32x4_t v0, v1;
  v0[0] = s[0]; v0[1] = s[1]; v0[2] = s[2]; v0[3] = s[3];
  v1[0] = s[4]; v1[1] = s[5]; v1[2] = s[6]; v1[3] = s[7];
  *(f32x4_t*)&lds[(t >> 5) * 256 + b8]     = v0;
  *(f32x4_t*)&lds[(t >> 5) * 256 + b8 + 4] = v1;
  __syncthreads();

  const int b = t;
  float g[8];
  #pragma unroll
  for (int j = 0; j < 8; ++j) g[j] = lds[j * 256 + b];
  float4* dst = (float4*)(out + (size_t)b * NOUT + blockIdx.x * 8);
  dst[0] = make_float4(g[0], g[1], g[2], g[3]);
  dst[1] = make_float4(g[4], g[5], g[6], g[7]);
}

extern "C" void kernel_launch(void* const* d_in, const int* in_sizes, int n_in,
                              void* d_out, int out_size, void* d_ws, size_t ws_size,
                              hipStream_t stream) {
  const float* input = (const float*)d_in[0];   // (256, 1024)
  const float* coef  = (const float*)d_in[1];   // (256, 16)
  const float* W     = (const float*)d_in[2];   // (1024, 1024, 16) -> (1024, 16384)
  const float* bias  = (const float*)d_in[3];   // (1024, 16)
  float* out = (float*)d_out;                   // (256, 1024)

  unsigned short* X    = (unsigned short*)d_ws;                               // 8 MiB bf16
  unsigned short* part = (unsigned short*)((char*)d_ws + (size_t)M * KTOT * 2); // 16 MiB bf16

  build_x_kernel<<<(M * 1024) / 256, 256, 0, stream>>>(input, coef, X);
  gemm_kernel<<<256, 512, 0, stream>>>(X, W, part);
  reduce_bias_kernel<<<NOUT / 8, 256, 0, stream>>>(part, bias, coef, out);
}